// Round 3
// baseline (233.911 us; speedup 1.0000x reference)
//
#include <hip/hip_runtime.h>
#include <hip/hip_bf16.h>

#define B_   16
#define CI_  32
#define H_   224
#define W_   224
#define CO_  32
#define OH_  222
#define OW_  222
#define HW_  (H_*W_)     // 50176
#define K_   288         // CI_*9

// Rolling-pipeline geometry: 256 thr / 4 waves; step = 4 oh rows x 64 ow x 32 co.
// LDS = ring of 10 row-slabs (66 px x 32 ci bf16 = 4224 B each) = 42,240 B
// -> exactly 3 blocks/CU; grid 768 = 3 x 256 CUs (no tail blocks).
#define OWTW   64
#define PXT_   66                // 64 + 2 col halo
#define NPAIR  33                // float2 pixel-pair tasks per row
#define RING   10
#define SLABB  (PXT_*CI_*2)      // 4224 B per row slab
#define CHROWS 20                // oh rows per block (5 steps of 4)
#define NCHUNK 12                // ceil(222/20)
#define NBLK   (NCHUNK*4*B_)     // 768

typedef __attribute__((ext_vector_type(8))) short short8;   // 8 bf16 = 16B
typedef __attribute__((ext_vector_type(4))) float float4v;  // MFMA C/D
typedef float float4u __attribute__((ext_vector_type(4), aligned(4)));

// LDS swizzle (verified R2: conflicts 3.8M -> 0.68M): XOR bits 4-6 with bits 7-9.
// Bijective involution within each 128 B pixel-pair region; slab base 4224 B is
// 128B-aligned so ring slabs preserve the property. Same formula on write & read.
__device__ __forceinline__ unsigned swz(unsigned L) {
    return L ^ (((L >> 7) & 7u) << 4);
}

__device__ __forceinline__ int wrap10(int v) {   // v in [0, 29]
    if (v >= 20) return v - 20;
    if (v >= 10) return v - 10;
    return v;
}

// ---------------- weights: w[co][ci][kh][kw] fp32 -> wbf[co][g][ci] bf16 ----------------
__global__ void wprep(const float* __restrict__ w, unsigned short* __restrict__ wbf) {
    int idx = blockIdx.x * 256 + threadIdx.x;
    if (idx >= CO_ * K_) return;
    int co  = idx / K_;
    int rem = idx - co * K_;
    int ci  = rem / 9;
    int g   = rem - ci * 9;           // kh*3+kw
    unsigned int u = __float_as_uint(w[idx]);
    u = u + 0x7FFFu + ((u >> 16) & 1u);
    wbf[co * K_ + g * 32 + ci] = (unsigned short)(u >> 16);
}

// issue 32 independent float2 loads for one (row, pixel-pair) task (col-clamped)
__device__ __forceinline__ void load_pair(const float* __restrict__ xp, int c, float2* f2) {
    if (c + 1 < W_) {
#pragma unroll
        for (int i = 0; i < 32; ++i)
            f2[i] = *(const float2*)&xp[(size_t)i * HW_ + c];
    } else {                          // c >= 224 (owt=3 halo): both cols clamp to 223
#pragma unroll
        for (int i = 0; i < 32; ++i) {
            float v = xp[(size_t)i * HW_ + (W_ - 1)];
            f2[i] = make_float2(v, v);
        }
    }
}

// convert 32 float2 (ci-major, px-pair) -> 8 short8 and write swizzled pair region
__device__ __forceinline__ void cvt_write_pair(unsigned short* Xs, int slot, int j,
                                               const float2* f2) {
    union { short8 s8[8]; __hip_bfloat162 h2[32]; } u;
#pragma unroll
    for (int i = 0; i < 16; ++i) {
        u.h2[i]      = __float22bfloat162_rn(make_float2(f2[2*i].x, f2[2*i+1].x)); // even px
        u.h2[16 + i] = __float22bfloat162_rn(make_float2(f2[2*i].y, f2[2*i+1].y)); // odd px
    }
    const unsigned base = (unsigned)(slot * NPAIR + j) * 128u;
#pragma unroll
    for (int k = 0; k < 8; ++k)
        *(short8*)((char*)Xs + swz(base + (unsigned)k * 16u)) = u.s8[k];
}

// ---------------- rolling double-buffered fused conv ----------------
// Per step s (rows r_s = r0+4s .. r_s+3):
//   1) issue global loads for rows r_s+6..r_s+9 (next step) into VGPRs   [T14 issue-early]
//   2) compute step s from ring slots (r_s..r_s+5)%10  (LDS reads + MFMA + stores)
//   3) convert + ds_write prefetched rows to slots (r_s+6..r_s+9)%10     [T14 write-late]
//   4) __syncthreads
// Ring safety: rows r_s..r_s+9 are 10 consecutive -> distinct mod 10; slots being
// written in step s were last read in step s-1 (pre-barrier). One barrier/step.
__global__ __launch_bounds__(256, 3) void conv_fused(
    const float* __restrict__ x, const unsigned short* __restrict__ wbf,
    const float* __restrict__ bias, float* __restrict__ out)
{
    __shared__ unsigned short Xs[RING * PXT_ * CI_];   // 42,240 B

    const int t   = threadIdx.x;
    const int bid = blockIdx.x;
    // XCD swizzle (verified R1: WRITE 127->108 MB): the 4 ow-tiles of one
    // (b,chunk) land on the same XCD, temporally adjacent -> L2 merges the
    // partial output sectors. bijective: bid = 32u + 8*owt + xcd.
    const int xcd   = bid & 7;
    const int owt   = (bid >> 3) & 3;
    const int gid   = (bid >> 5) * 8 + xcd;        // 0..191 = b*12 + chunk
    const int b     = gid / NCHUNK;
    const int chunk = gid - b * NCHUNK;
    const int r0    = chunk * CHROWS;
    const int ow0   = owt * OWTW;
    const int NS    = min(5, (OH_ - r0 + 3) >> 2); // chunks 0-10: 5, chunk 11: 1

    const int lane = t & 63, wv = t >> 6;
    const int i16  = lane & 15, quad = lane >> 4;

    const float* xb = x + (size_t)b * CI_ * HW_;

    float2 f2[32];                                  // prefetch registers (64 VGPR)

    // ---- prologue: stage rows r0..r0+5 -> slots 0..5 (198 tasks) ----
    if (t < 6 * NPAIR) {
        const int tr = t / NPAIR, j = t - tr * NPAIR;
        int gr = r0 + tr; if (gr > H_ - 1) gr = H_ - 1;   // chunk 11 clamps; unread
        load_pair(xb + (size_t)gr * W_, ow0 + 2 * j, f2);
        cvt_write_pair(Xs, tr, j, f2);
    }
    __syncthreads();

    const float bv0 = bias[i16];
    const float bv1 = bias[16 + i16];
    const unsigned short* wr0 = wbf + (size_t)i16 * K_;          // co = i16
    const unsigned short* wr1 = wbf + (size_t)(16 + i16) * K_;   // co = 16+i16

    const int s_tr = t / NPAIR;        // steady-state stage task (threads 0..131)
    const int s_j  = t - s_tr * NPAIR;
    const int s_c  = ow0 + 2 * s_j;

    for (int s = 0; s < NS; ++s) {
        // ---- 1) issue next-step loads (before compute -> latency hidden) ----
        const bool pref = (t < 4 * NPAIR) && (s + 1 < NS);
        int slotW = 0;
        if (pref) {
            const int gr0 = r0 + 4 * s + 6 + s_tr;
            slotW = wrap10(4 * s + 6 + s_tr);
            const int gr = gr0 > H_ - 1 ? H_ - 1 : gr0;
            load_pair(xb + (size_t)gr * W_, s_c, f2);
        }
        __builtin_amdgcn_sched_barrier(0);   // pin load issue here (don't sink to use)

        // ---- 2) compute: wave wv -> oh = r0+4s+wv ----
        const int oh = r0 + 4 * s + wv;
        if (oh < OH_) {                      // wave-uniform guard; no early return
            float4v acc[4][2] = {};
            const int sl0 = 4 * s + wv;
#pragma unroll
            for (int g = 0; g < 9; ++g) {
                const int kh = g / 3, kw = g - kh * 3;
                const int sl = wrap10(sl0 + kh);
                const short8 b0 = *(const short8*)&wr0[g * 32 + quad * 8];
                const short8 b1 = *(const short8*)&wr1[g * 32 + quad * 8];
                const unsigned rowbase = (unsigned)(sl * SLABB) + (unsigned)quad * 16u;
#pragma unroll
                for (int ot = 0; ot < 4; ++ot) {
                    const unsigned L = rowbase + (unsigned)(ot * 16 + i16 + kw) * 64u;
                    const short8 a = *(const short8*)((const char*)Xs + swz(L));
                    acc[ot][0] = __builtin_amdgcn_mfma_f32_16x16x32_bf16(a, b0, acc[ot][0], 0, 0, 0);
                    acc[ot][1] = __builtin_amdgcn_mfma_f32_16x16x32_bf16(a, b1, acc[ot][1], 0, 0, 0);
                }
            }
            // epilogue: per (ot,half) one dwordx4 -> 64B-contiguous runs per co-plane
            const size_t o0 = ((size_t)(b * CO_ + i16) * OH_ + oh) * (size_t)OW_;
            const size_t o1 = ((size_t)(b * CO_ + 16 + i16) * OH_ + oh) * (size_t)OW_;
#pragma unroll
            for (int ot = 0; ot < 4; ++ot) {
                const int owq = ow0 + ot * 16 + quad * 4;
                float4u v0 = { acc[ot][0][0] + bv0, acc[ot][0][1] + bv0,
                               acc[ot][0][2] + bv0, acc[ot][0][3] + bv0 };
                float4u v1 = { acc[ot][1][0] + bv1, acc[ot][1][1] + bv1,
                               acc[ot][1][2] + bv1, acc[ot][1][3] + bv1 };
                if (owq + 3 < OW_) {
                    *(float4u*)&out[o0 + owq] = v0;
                    *(float4u*)&out[o1 + owq] = v1;
                } else {
#pragma unroll
                    for (int r = 0; r < 4; ++r)
                        if (owq + r < OW_) {
                            out[o0 + owq + r] = acc[ot][0][r] + bv0;
                            out[o1 + owq + r] = acc[ot][1][r] + bv1;
                        }
                }
            }
        }

        // ---- 3) write-late: convert prefetched rows into ring (disjoint slots) ----
        if (pref) cvt_write_pair(Xs, slotW, s_j, f2);
        // ---- 4) one barrier per step ----
        __syncthreads();
    }
}

extern "C" void kernel_launch(void* const* d_in, const int* in_sizes, int n_in,
                              void* d_out, int out_size, void* d_ws, size_t ws_size,
                              hipStream_t stream) {
    const float* x    = (const float*)d_in[0];
    const float* w    = (const float*)d_in[1];
    const float* bias = (const float*)d_in[2];
    float* out        = (float*)d_out;
    unsigned short* wbf = (unsigned short*)d_ws;                 // 18,432 B

    wprep<<<(CO_ * K_ + 255) / 256, 256, 0, stream>>>(w, wbf);
    conv_fused<<<dim3(NBLK), 256, 0, stream>>>(x, wbf, bias, out);
}